// Round 6
// baseline (77.439 us; speedup 1.0000x reference)
//
#include <hip/hip_runtime.h>
#include <stdint.h>

// ContrastiveLoss: B=8192, D=1024, n=2048, T=0.5
// K1: row-normalize f32 -> bf16 (one wave per row), zero denom/sumsim
// K2: 256x256 MFMA GEMM, 8-phase m201-style schedule (2 K-tiles/iter),
//     one-phase-ahead fragment prefetch, counted vmcnt gates (P3/P7 only),
//     XCD-chunked mapping; epilogue: exp-row-sum + triu sum
// K3: scalar finalize

#define BDIM 1024
#define BROWS 8192
#define NROWS 2048

#define BM 256
#define BN 256
#define BK 64

typedef __attribute__((ext_vector_type(8))) short bf16x8;
typedef __attribute__((ext_vector_type(4))) float f32x4;

static __device__ __forceinline__ unsigned short f2bf(float x) {
  union { float f; unsigned int u; } a; a.f = x;
  unsigned int u = a.u;
  return (unsigned short)((u + 0x7fffu + ((u >> 16) & 1u)) >> 16);  // RNE
}

static __device__ __forceinline__ void gload_lds16(const unsigned short* g, unsigned short* l) {
  __builtin_amdgcn_global_load_lds(
      (const __attribute__((address_space(1))) uint32_t*)(const void*)g,
      (__attribute__((address_space(3))) uint32_t*)(void*)l,
      16, 0, 0);
}

__global__ __launch_bounds__(256) void normalize_kernel(const float* __restrict__ emb,
                                                        unsigned short* __restrict__ zb,
                                                        float* __restrict__ denom,
                                                        float* __restrict__ sumsim) {
  const int w = threadIdx.x >> 6;
  const int lane = threadIdx.x & 63;
  const int row = blockIdx.x * 4 + w;
  const float4* src = reinterpret_cast<const float4*>(emb + (size_t)row * BDIM);
  float4 v[4];
  float ss = 0.f;
#pragma unroll
  for (int i = 0; i < 4; i++) {
    v[i] = src[lane + i * 64];
    ss += v[i].x * v[i].x + v[i].y * v[i].y + v[i].z * v[i].z + v[i].w * v[i].w;
  }
#pragma unroll
  for (int m = 1; m < 64; m <<= 1) ss += __shfl_xor(ss, m);
  const float inv = rsqrtf(ss);
  ushort4* dst = reinterpret_cast<ushort4*>(zb + (size_t)row * BDIM);
#pragma unroll
  for (int i = 0; i < 4; i++) {
    ushort4 o;
    o.x = f2bf(v[i].x * inv);
    o.y = f2bf(v[i].y * inv);
    o.z = f2bf(v[i].z * inv);
    o.w = f2bf(v[i].w * inv);
    dst[lane + i * 64] = o;
  }
  if (blockIdx.x < NROWS / 4 && lane == 0) denom[row] = 0.f;
  if (blockIdx.x == 0 && threadIdx.x == 0) sumsim[0] = 0.f;
}

// ---------------- GEMM ----------------
// LDS: As[2][256*64] + Bs[2][256*64] bf16 = 128 KB. Tile 2i -> buf0, 2i+1 -> buf1.
// Row = 64 bf16 = 8x16B slots; stored slot s of row r at s^(r&7) via pre-swizzled
// global source (2-way-free ds_read_b128).
// Waves 2Mx4N: wave (WR,WC) owns rows [WR*128,+128) x cols [WC*64,+64).
// Fragment groups: fA0 (m0-3), fA1 (m4-7), fB0 (n0-1), fB1 (n2-3).
// Quadrant snake: t0: (A0B0)(A1B0)(A1B1)(A0B1); t1: (A1B0)(A0B0)(A0B1)(A1B1).
// Phase p: {stage unit; [gate]; BAR; lgkm0; MFMA quad_p (prev phase's frags);
//           ds_reads for quad_{p+1}; BAR}.
// Stages: P2:t0'B0 P3:t0'B1 P4:t0'A0 P5:t0'A1 P6:t1'A0 P7:t1'A1,t1'B0,t1'B1.
// Gates: P3 vmcnt(4) [prev t1' landed], P7 vmcnt(8) [t0' landed]. Never 0 mid-loop.

__global__ __launch_bounds__(512, 2) void gemm_fused(const unsigned short* __restrict__ zb,
                                                     float* __restrict__ denom,
                                                     float* __restrict__ sumsim) {
  __shared__ unsigned short As[2][BM * BK];
  __shared__ unsigned short Bs[2][BN * BK];

  const int bx = blockIdx.x;           // 0..255
  const int xcd = bx & 7;
  const int idx = bx >> 3;             // 0..31
  const int jb = xcd * 4 + (idx & 3);  // 0..31
  const int ib = idx >> 2;             // 0..7
  const int i0 = ib * BM;
  const int j0 = jb * BN;

  const int t = threadIdx.x;
  const int lane = t & 63;
  const int w = t >> 6;
  const int WR = w >> 2;               // 0..1
  const int WC = w & 3;                // 0..3

  // staging: one STG covers 64 rows (8 rows/wave); stored slot lane&7 holds
  // fetched chunk (lane&7)^rsh
  const int rsh = lane >> 3;
  const int slsrc = (lane & 7) ^ rsh;
  const int aw = w * 8;

  // reads
  const int q = lane >> 4;
  const int rsub = lane & 15;
  const int sA0 = q ^ (rsub & 7);

  f32x4 acc[8][4] = {};
  bf16x8 fA0[4][2], fA1[4][2], fB0[2][2], fB1[2][2];

#define STG_A(buf, r0, kk) \
  gload_lds16(zb + (size_t)(i0 + (r0) + aw + rsh) * BDIM + (kk) + slsrc * 8, &As[buf][((r0) + aw) * BK])
#define STG_B(buf, r0, kk) \
  gload_lds16(zb + (size_t)(j0 + (r0) + aw + rsh) * BDIM + (kk) + slsrc * 8, &Bs[buf][((r0) + aw) * BK])

#define LDA(buf, mm, kk) \
  (*reinterpret_cast<const bf16x8*>(&As[buf][(size_t)(WR * 128 + (mm) * 16 + rsub) * BK + ((sA0 ^ ((kk) * 4)) * 8)]))
#define LDB(buf, nn, kk) \
  (*reinterpret_cast<const bf16x8*>(&Bs[buf][(size_t)(WC * 64 + (nn) * 16 + rsub) * BK + ((sA0 ^ ((kk) * 4)) * 8)]))

#define RD_A0(buf) \
  _Pragma("unroll") for (int mm = 0; mm < 4; mm++) { fA0[mm][0] = LDA(buf, mm, 0); fA0[mm][1] = LDA(buf, mm, 1); }
#define RD_A1(buf) \
  _Pragma("unroll") for (int mm = 0; mm < 4; mm++) { fA1[mm][0] = LDA(buf, mm + 4, 0); fA1[mm][1] = LDA(buf, mm + 4, 1); }
#define RD_B0(buf) \
  _Pragma("unroll") for (int nn = 0; nn < 2; nn++) { fB0[nn][0] = LDB(buf, nn, 0); fB0[nn][1] = LDB(buf, nn, 1); }
#define RD_B1(buf) \
  _Pragma("unroll") for (int nn = 0; nn < 2; nn++) { fB1[nn][0] = LDB(buf, nn + 2, 0); fB1[nn][1] = LDB(buf, nn + 2, 1); }

#define MFMA16(MB, NB, FA, FB)                                                                     \
  _Pragma("unroll") for (int mm = 0; mm < 4; mm++)                                                 \
  _Pragma("unroll") for (int nn = 0; nn < 2; nn++) {                                               \
    acc[(MB) + mm][(NB) + nn] =                                                                    \
        __builtin_amdgcn_mfma_f32_16x16x32_bf16(FA[mm][0], FB[nn][0], acc[(MB) + mm][(NB) + nn], 0, 0, 0); \
    acc[(MB) + mm][(NB) + nn] =                                                                    \
        __builtin_amdgcn_mfma_f32_16x16x32_bf16(FA[mm][1], FB[nn][1], acc[(MB) + mm][(NB) + nn], 0, 0, 0); \
  }

#define BAR() __builtin_amdgcn_s_barrier()
#define OPEN()                                              \
  BAR();                                                    \
  asm volatile("s_waitcnt lgkmcnt(0)" ::: "memory");        \
  __builtin_amdgcn_sched_barrier(0);                        \
  __builtin_amdgcn_s_setprio(1)
#define CLOSE()                                             \
  __builtin_amdgcn_sched_barrier(0);                        \
  BAR()

  // ---- prologue: stage tiles 0 (buf0) and 1 (buf1); pre-read t0.(A0,B0) ----
  STG_A(0, 0, 0);   STG_A(0, 64, 0);   STG_A(0, 128, 0); STG_A(0, 192, 0);
  STG_B(0, 0, 0);   STG_B(0, 64, 0);   STG_B(0, 128, 0); STG_B(0, 192, 0);
  STG_A(1, 0, BK);  STG_A(1, 64, BK);  STG_A(1, 128, BK); STG_A(1, 192, BK);
  STG_B(1, 0, BK);  STG_B(1, 64, BK);  STG_B(1, 128, BK); STG_B(1, 192, BK);
  asm volatile("s_waitcnt vmcnt(8)" ::: "memory");  // tile0 landed; tile1 in flight
  BAR();
  RD_A0(0); RD_B0(0);

#pragma unroll 1
  for (int it = 0; it < 8; ++it) {
    const int pf = (it < 7);
    const int kk2 = (2 * it + 2) * BK;
    const int kk3 = (2 * it + 3) * BK;

    // P0: MFMA t0.(A0,B0); reads fA1(t0)
    OPEN(); MFMA16(0, 0, fA0, fB0); __builtin_amdgcn_s_setprio(0);
    RD_A1(0);
    CLOSE();

    // P1: MFMA t0.(A1,B0); reads fB1(t0)
    OPEN(); MFMA16(4, 0, fA1, fB0); __builtin_amdgcn_s_setprio(0);
    RD_B1(0);
    CLOSE();

    // P2: stage t0'B0; MFMA t0.(A1,B1); no reads
    if (pf) { STG_B(0, 0, kk2); STG_B(0, 64, kk2); }
    OPEN(); MFMA16(4, 2, fA1, fB1); __builtin_amdgcn_s_setprio(0);
    CLOSE();

    // P3: stage t0'B1; GATE; MFMA t0.(A0,B1); reads fA1(t1)+fB0(t1) [12]
    if (pf) {
      STG_B(0, 128, kk2); STG_B(0, 192, kk2);
      asm volatile("s_waitcnt vmcnt(4)" ::: "memory");
    } else {
      asm volatile("s_waitcnt vmcnt(0)" ::: "memory");
    }
    OPEN(); MFMA16(0, 2, fA0, fB1); __builtin_amdgcn_s_setprio(0);
    RD_A1(1); RD_B0(1);
    asm volatile("s_waitcnt lgkmcnt(8)" ::: "memory");
    CLOSE();

    // P4: stage t0'A0; MFMA t1.(A1,B0); reads fA0(t1)
    if (pf) { STG_A(0, 0, kk2); STG_A(0, 64, kk2); }
    OPEN(); MFMA16(4, 0, fA1, fB0); __builtin_amdgcn_s_setprio(0);
    RD_A0(1);
    CLOSE();

    // P5: stage t0'A1; MFMA t1.(A0,B0); reads fB1(t1)
    if (pf) { STG_A(0, 128, kk2); STG_A(0, 192, kk2); }
    OPEN(); MFMA16(0, 0, fA0, fB0); __builtin_amdgcn_s_setprio(0);
    RD_B1(1);
    CLOSE();

    // P6: stage t1'A0; MFMA t1.(A0,B1); no reads
    if (pf) { STG_A(1, 0, kk3); STG_A(1, 64, kk3); }
    OPEN(); MFMA16(0, 2, fA0, fB1); __builtin_amdgcn_s_setprio(0);
    CLOSE();

    // P7: stage t1'A1 + t1'B0 + t1'B1; GATE; MFMA t1.(A1,B1); reads fA0+fB0(t0') [12]
    if (pf) {
      STG_A(1, 128, kk3); STG_A(1, 192, kk3);
      STG_B(1, 0, kk3);   STG_B(1, 64, kk3);
      STG_B(1, 128, kk3); STG_B(1, 192, kk3);
      asm volatile("s_waitcnt vmcnt(8)" ::: "memory");
    }
    OPEN(); MFMA16(4, 2, fA1, fB1); __builtin_amdgcn_s_setprio(0);
    if (pf) {
      RD_A0(0); RD_B0(0);
      asm volatile("s_waitcnt lgkmcnt(8)" ::: "memory");
    }
    CLOSE();
  }

  // ---- epilogue ----
  const int hi = lane >> 4;
  const int col_l = lane & 15;
  float ssim = 0.f;
#pragma unroll
  for (int m = 0; m < 8; m++) {
    const int gibase = i0 + WR * 128 + m * 16 + hi * 4;
#pragma unroll
    for (int r = 0; r < 4; r++) {
      const int gi = gibase + r;
      float dsum = 0.f;
#pragma unroll
      for (int n = 0; n < 4; n++) {
        const int gj = j0 + WC * 64 + n * 16 + col_l;
        const float s = acc[m][n][r] * 2.0f;
        const float e = __expf(s);
        if (gj != gi) dsum += e;               // denom excludes diagonal
        if (gj < NROWS && gi < gj) ssim += s;  // triu(rows[:, :n], k=1)
      }
      dsum += __shfl_xor(dsum, 1);
      dsum += __shfl_xor(dsum, 2);
      dsum += __shfl_xor(dsum, 4);
      dsum += __shfl_xor(dsum, 8);
      if (col_l == 0) atomicAdd(&denom[gi], dsum);
    }
  }
#pragma unroll
  for (int msk = 1; msk < 64; msk <<= 1) ssim += __shfl_xor(ssim, msk);
  if (lane == 0 && j0 < NROWS) atomicAdd(sumsim, ssim);
}

__global__ __launch_bounds__(1024) void finalize(const float* __restrict__ denom,
                                                 const float* __restrict__ sumsim,
                                                 float* __restrict__ out) {
  const int t = threadIdx.x;
  double s = 0.0;
#pragma unroll
  for (int i = t; i < NROWS; i += 1024) {
    s += (double)(NROWS - 1 - i) * log((double)denom[i]);
  }
#pragma unroll
  for (int m = 1; m < 64; m <<= 1) s += __shfl_xor(s, m);
  __shared__ double ws_[16];
  if ((t & 63) == 0) ws_[t >> 6] = s;
  __syncthreads();
  if (t == 0) {
    double tot = 0.0;
#pragma unroll
    for (int i = 0; i < 16; i++) tot += ws_[i];
    const double loss = tot - (double)sumsim[0];
    out[0] = (float)(-2.0 / (double)NROWS * (double)(NROWS - 1) * loss);
  }
}

extern "C" void kernel_launch(void* const* d_in, const int* in_sizes, int n_in,
                              void* d_out, int out_size, void* d_ws, size_t ws_size,
                              hipStream_t stream) {
  const float* emb = (const float*)d_in[0];
  unsigned short* zb = (unsigned short*)d_ws;
  float* denom = (float*)((char*)d_ws + (size_t)BROWS * BDIM * 2);
  float* sumsim = denom + NROWS;
  float* out = (float*)d_out;

  normalize_kernel<<<BROWS / 4, 256, 0, stream>>>(emb, zb, denom, sumsim);
  gemm_fused<<<(BROWS / BN) * (NROWS / BM), 512, 0, stream>>>(zb, denom, sumsim);
  finalize<<<1, 1024, 0, stream>>>(denom, sumsim, out);
}